// Round 5
// baseline (565.441 us; speedup 1.0000x reference)
//
#include <hip/hip_runtime.h>
#include <math.h>

#define IN_F 64
#define HID 128
#define NCLS 10

typedef unsigned int uint;

// bf16 round-to-nearest-even, bit arithmetic (no header intrinsics)
__device__ inline uint bf16r(float f) {
    uint u = __float_as_uint(f);
    u += 0x7fffu + ((u >> 16) & 1u);
    return u >> 16;
}
__device__ inline uint pack2(float a, float b) {
    return bf16r(a) | (bf16r(b) << 16);
}
__device__ inline float blo(uint u) { return __uint_as_float(u << 16); }
__device__ inline float bhi(uint u) { return __uint_as_float(u & 0xffff0000u); }

// ---------- utility ----------
__global__ void k_zero_int(int* __restrict__ p, int n) {
    int i = blockIdx.x * blockDim.x + threadIdx.x;
    if (i < n) p[i] = 0;
}

__global__ void k_zero_out(float* __restrict__ out) {
    if (threadIdx.x < NCLS) out[threadIdx.x] = 0.f;
}

// ---------- degree histogram over targets ----------
__global__ void k_hist(const int* __restrict__ col, int* __restrict__ cnt, int E) {
    int i = blockIdx.x * blockDim.x + threadIdx.x;
    if (i < E) atomicAdd(&cnt[col[i]], 1);
}

// ---------- 3-kernel exclusive scan (cnt -> rowptr) ----------
__global__ void k_blocksum(const int* __restrict__ cnt, int* __restrict__ bsum, int n) {
    __shared__ int s[256];
    int i = blockIdx.x * 256 + threadIdx.x;
    s[threadIdx.x] = (i < n) ? cnt[i] : 0;
    __syncthreads();
    for (int off = 128; off > 0; off >>= 1) {
        if (threadIdx.x < off) s[threadIdx.x] += s[threadIdx.x + off];
        __syncthreads();
    }
    if (threadIdx.x == 0) bsum[blockIdx.x] = s[0];
}

__global__ void k_scan_bsum(const int* __restrict__ bsum, int* __restrict__ boff, int nb,
                            int* __restrict__ rowptr, int n, int E) {
    __shared__ int s[512];
    int t = threadIdx.x;
    int v = (t < nb) ? bsum[t] : 0;
    s[t] = v;
    __syncthreads();
    for (int off = 1; off < 512; off <<= 1) {
        int tmp = (t >= off) ? s[t - off] : 0;
        __syncthreads();
        s[t] += tmp;
        __syncthreads();
    }
    if (t < nb) boff[t] = s[t] - v;  // exclusive
    if (t == 0) rowptr[n] = E;
}

// scan within block + write rowptr, pos (=rowptr copy), dis — fused
__global__ void k_scan_final(const int* __restrict__ cnt, const int* __restrict__ boff,
                             int* __restrict__ rowptr, int* __restrict__ pos,
                             float* __restrict__ dis, int n) {
    __shared__ int s[256];
    int i = blockIdx.x * 256 + threadIdx.x;
    int v = (i < n) ? cnt[i] : 0;
    s[threadIdx.x] = v;
    __syncthreads();
    for (int off = 1; off < 256; off <<= 1) {
        int tmp = (threadIdx.x >= off) ? s[threadIdx.x - off] : 0;
        __syncthreads();
        s[threadIdx.x] += tmp;
        __syncthreads();
    }
    if (i < n) {
        int rp = boff[blockIdx.x] + s[threadIdx.x] - v;  // exclusive
        rowptr[i] = rp;
        pos[i] = rp;
        dis[i] = rsqrtf(1.0f + (float)v);
    }
}

// ---------- CSR fill: src list sorted by target ----------
__global__ void k_fill(const int* __restrict__ row, const int* __restrict__ col,
                       int* __restrict__ pos, int* __restrict__ src, int E) {
    int e = blockIdx.x * blockDim.x + threadIdx.x;
    if (e >= E) return;
    int p = atomicAdd(&pos[col[e]], 1);
    src[p] = row[e];
}

// ---------- xsb = bf16(x * dis[node]), 32 uints (64 bf16) per row ----------
__global__ void k_xs(const float* __restrict__ x, const float* __restrict__ dis,
                     uint* __restrict__ xsb, int n8) {
    int i = blockIdx.x * blockDim.x + threadIdx.x;
    if (i >= n8) return;
    float d = dis[i >> 3];  // 8 uint4s per node
    float4 u = ((const float4*)x)[i * 2];
    float4 v = ((const float4*)x)[i * 2 + 1];
    uint4 o;
    o.x = pack2(u.x * d, u.y * d);
    o.y = pack2(u.z * d, u.w * d);
    o.z = pack2(v.x * d, v.y * d);
    o.w = pack2(v.z * d, v.w * d);
    ((uint4*)xsb)[i] = o;
}

// ---------- fused gather1 + GEMM1 + bias + relu ----------
// wave per node; 8 lanes x uint4(8 bf16) per row; 8 edge slots, unroll x2
// => 16 independent 128B row-loads in flight per wave
__global__ __launch_bounds__(256) void k_l1(const uint* __restrict__ xsb,
                                            const int* __restrict__ src,
                                            const int* __restrict__ rowptr,
                                            const float* __restrict__ dis,
                                            const float* __restrict__ W1,
                                            const float* __restrict__ b1,
                                            uint* __restrict__ hb, int n) {
    __shared__ float hacc[4][64];
    int w = threadIdx.x >> 6, lane = threadIdx.x & 63;
    int slot = lane >> 3;  // edge slot 0..7
    int ch = lane & 7;     // uint4 chunk within row (bf16 [8ch..8ch+8))
    int i = blockIdx.x * 4 + w;
    float a0 = 0.f, a1 = 0.f, a2 = 0.f, a3 = 0.f, a4 = 0.f, a5 = 0.f, a6 = 0.f,
          a7 = 0.f;
    float d = 0.f;
#define ACC8(v)                                                                \
    {                                                                          \
        a0 += blo(v.x); a1 += bhi(v.x); a2 += blo(v.y); a3 += bhi(v.y);        \
        a4 += blo(v.z); a5 += bhi(v.z); a6 += blo(v.w); a7 += bhi(v.w);        \
    }
    if (i < n) {
        d = dis[i];
        if (slot == 0) {  // self-loop term counted once
            uint4 v = ((const uint4*)(xsb + (size_t)i * 32))[ch];
            ACC8(v);
        }
        int end = rowptr[i + 1];
        int e = rowptr[i] + slot;
        for (; e + 8 < end; e += 16) {
            int s0 = src[e];
            int s1 = src[e + 8];
            uint4 v0 = ((const uint4*)(xsb + (size_t)s0 * 32))[ch];
            uint4 v1 = ((const uint4*)(xsb + (size_t)s1 * 32))[ch];
            ACC8(v0);
            ACC8(v1);
        }
        if (e < end) {
            int s = src[e];
            uint4 v = ((const uint4*)(xsb + (size_t)s * 32))[ch];
            ACC8(v);
        }
    }
#undef ACC8
    // combine 8 edge slots: xor butterfly over lane bits 3,4,5
#pragma unroll
    for (int off = 8; off < 64; off <<= 1) {
        a0 += __shfl_xor(a0, off, 64);
        a1 += __shfl_xor(a1, off, 64);
        a2 += __shfl_xor(a2, off, 64);
        a3 += __shfl_xor(a3, off, 64);
        a4 += __shfl_xor(a4, off, 64);
        a5 += __shfl_xor(a5, off, 64);
        a6 += __shfl_xor(a6, off, 64);
        a7 += __shfl_xor(a7, off, 64);
    }
    if (slot == 0) {
        float4 lo = make_float4(a0 * d, a1 * d, a2 * d, a3 * d);
        float4 hi = make_float4(a4 * d, a5 * d, a6 * d, a7 * d);
        ((float4*)&hacc[w][ch * 8])[0] = lo;
        ((float4*)&hacc[w][ch * 8])[1] = hi;
    }
    __syncthreads();
    if (i < n) {
        // columns 2*lane, 2*lane+1 -> packed bf16 pair
        float2 bv = ((const float2*)b1)[lane];
        float h0 = bv.x, h1 = bv.y;
#pragma unroll
        for (int k = 0; k < IN_F; ++k) {
            float a = hacc[w][k];  // LDS broadcast
            float2 wv = ((const float2*)(W1 + k * HID))[lane];
            h0 = fmaf(a, wv.x, h0);
            h1 = fmaf(a, wv.y, h1);
        }
        hb[(size_t)i * 64 + lane] = pack2(fmaxf(h0, 0.f), fmaxf(h1, 0.f));
    }
}

// ---------- h2sb[i, c2] = bf16 pair of dis[i] * (h[i,:] @ W2[:, 2c2:2c2+2]) ----------
// thread per (node, class-pair); h row is 64 uints (128 bf16)
__global__ void k_h2s(const uint* __restrict__ hb, const float* __restrict__ W2,
                      const float* __restrict__ dis, uint* __restrict__ h2sb, int n) {
    int idx = blockIdx.x * blockDim.x + threadIdx.x;
    if (idx >= n * 5) return;
    int node = idx / 5;
    int c2 = idx - node * 5;
    const uint4* hr = (const uint4*)(hb + (size_t)node * 64);
    float acc0 = 0.f, acc1 = 0.f;
#pragma unroll
    for (int k4 = 0; k4 < 16; ++k4) {
        uint4 v = hr[k4];
        int kb = k4 * 8;
        float e0 = blo(v.x), e1 = bhi(v.x), e2 = blo(v.y), e3 = bhi(v.y);
        float e4 = blo(v.z), e5 = bhi(v.z), e6 = blo(v.w), e7 = bhi(v.w);
        float2 w0 = *(const float2*)(W2 + (kb + 0) * NCLS + 2 * c2);
        float2 w1 = *(const float2*)(W2 + (kb + 1) * NCLS + 2 * c2);
        float2 w2 = *(const float2*)(W2 + (kb + 2) * NCLS + 2 * c2);
        float2 w3 = *(const float2*)(W2 + (kb + 3) * NCLS + 2 * c2);
        float2 w4 = *(const float2*)(W2 + (kb + 4) * NCLS + 2 * c2);
        float2 w5 = *(const float2*)(W2 + (kb + 5) * NCLS + 2 * c2);
        float2 w6 = *(const float2*)(W2 + (kb + 6) * NCLS + 2 * c2);
        float2 w7 = *(const float2*)(W2 + (kb + 7) * NCLS + 2 * c2);
        acc0 = fmaf(e0, w0.x, acc0); acc1 = fmaf(e0, w0.y, acc1);
        acc0 = fmaf(e1, w1.x, acc0); acc1 = fmaf(e1, w1.y, acc1);
        acc0 = fmaf(e2, w2.x, acc0); acc1 = fmaf(e2, w2.y, acc1);
        acc0 = fmaf(e3, w3.x, acc0); acc1 = fmaf(e3, w3.y, acc1);
        acc0 = fmaf(e4, w4.x, acc0); acc1 = fmaf(e4, w4.y, acc1);
        acc0 = fmaf(e5, w5.x, acc0); acc1 = fmaf(e5, w5.y, acc1);
        acc0 = fmaf(e6, w6.x, acc0); acc1 = fmaf(e6, w6.y, acc1);
        acc0 = fmaf(e7, w7.x, acc0); acc1 = fmaf(e7, w7.y, acc1);
    }
    float dd = dis[node];
    h2sb[(size_t)node * 8 + c2] = pack2(acc0 * dd, acc1 * dd);
}

// ---------- fused gather2 + b2 + log-softmax + mean-reduce ----------
// h2sb rows: 8 uints (uints 0..4 hold 10 bf16; 5..7 pad, never read)
__global__ void k_lsm2(const uint* __restrict__ h2sb, const int* __restrict__ src,
                       const int* __restrict__ rowptr, const float* __restrict__ dis,
                       const float* __restrict__ b2, float* __restrict__ out, int n,
                       float inv_n) {
    __shared__ float sred[NCLS];
    if (threadIdx.x < NCLS) sred[threadIdx.x] = 0.f;
    __syncthreads();
    int i = blockIdx.x * blockDim.x + threadIdx.x;
    float loc[NCLS];
#pragma unroll
    for (int c = 0; c < NCLS; ++c) loc[c] = 0.f;
    if (i < n) {
        float a[NCLS], a2[NCLS];
#define DEC10(base, q, q4)                                                     \
    float base##0 = blo(q.x), base##1 = bhi(q.x), base##2 = blo(q.y),          \
          base##3 = bhi(q.y), base##4 = blo(q.z), base##5 = bhi(q.z),          \
          base##6 = blo(q.w), base##7 = bhi(q.w), base##8 = blo(q4),           \
          base##9 = bhi(q4);
        {
            const uint* r = h2sb + (size_t)i * 8;
            uint4 q = *(const uint4*)r;
            uint q4 = r[4];
            DEC10(s, q, q4);
            a[0] = s0; a[1] = s1; a[2] = s2; a[3] = s3; a[4] = s4;
            a[5] = s5; a[6] = s6; a[7] = s7; a[8] = s8; a[9] = s9;
#pragma unroll
            for (int c = 0; c < NCLS; ++c) a2[c] = 0.f;
        }
        int beg = rowptr[i], end = rowptr[i + 1];
        int e = beg;
        for (; e + 1 < end; e += 2) {  // 2 independent accumulator chains
            const uint* r0 = h2sb + (size_t)src[e] * 8;
            const uint* r1 = h2sb + (size_t)src[e + 1] * 8;
            uint4 p0 = *(const uint4*)r0;
            uint p04 = r0[4];
            uint4 p1 = *(const uint4*)r1;
            uint p14 = r1[4];
            DEC10(u, p0, p04);
            DEC10(v, p1, p14);
            a[0] += u0; a[1] += u1; a[2] += u2; a[3] += u3; a[4] += u4;
            a[5] += u5; a[6] += u6; a[7] += u7; a[8] += u8; a[9] += u9;
            a2[0] += v0; a2[1] += v1; a2[2] += v2; a2[3] += v3; a2[4] += v4;
            a2[5] += v5; a2[6] += v6; a2[7] += v7; a2[8] += v8; a2[9] += v9;
        }
        if (e < end) {
            const uint* r = h2sb + (size_t)src[e] * 8;
            uint4 q = *(const uint4*)r;
            uint q4 = r[4];
            DEC10(t, q, q4);
            a[0] += t0; a[1] += t1; a[2] += t2; a[3] += t3; a[4] += t4;
            a[5] += t5; a[6] += t6; a[7] += t7; a[8] += t8; a[9] += t9;
        }
#undef DEC10
        float d = dis[i];
        float vv[NCLS];
        float m = -1e30f;
#pragma unroll
        for (int c = 0; c < NCLS; ++c) {
            vv[c] = b2[c] + d * (a[c] + a2[c]);
            m = fmaxf(m, vv[c]);
        }
        float se = 0.f;
#pragma unroll
        for (int c = 0; c < NCLS; ++c) se += __expf(vv[c] - m);
        float lse = m + __logf(se);
#pragma unroll
        for (int c = 0; c < NCLS; ++c) loc[c] = vv[c] - lse;
    }
#pragma unroll
    for (int c = 0; c < NCLS; ++c) atomicAdd(&sred[c], loc[c]);
    __syncthreads();
    if (threadIdx.x < NCLS) atomicAdd(&out[threadIdx.x], sred[threadIdx.x] * inv_n);
}

extern "C" void kernel_launch(void* const* d_in, const int* in_sizes, int n_in,
                              void* d_out, int out_size, void* d_ws, size_t ws_size,
                              hipStream_t stream) {
    const float* x = (const float*)d_in[0];
    const int* eidx = (const int*)d_in[1];
    const float* W1 = (const float*)d_in[2];
    const float* b1 = (const float*)d_in[3];
    const float* W2 = (const float*)d_in[4];
    const float* b2 = (const float*)d_in[5];
    float* out = (float*)d_out;

    const int N = in_sizes[0] / IN_F;  // 100000
    const int E = in_sizes[1] / 2;     // 1600000
    const int* row = eidx;             // sources
    const int* col = eidx + E;         // targets

    const int NB = (N + 255) / 256;  // scan blocks (391 <= 512)

    // workspace layout (4-byte words, 1024-word aligned)
    size_t o = 0;
    auto alloc = [&](size_t words) {
        size_t r = o;
        o += (words + 1023) & ~(size_t)1023;
        return r;
    };
    float* ws = (float*)d_ws;
    float* dis = ws + alloc(N);
    uint* xsb = (uint*)(ws + alloc((size_t)N * 32));   // bf16 x*dis, 128B rows
    uint* hb = (uint*)(ws + alloc((size_t)N * 64));    // bf16 relu(h), 256B rows
    uint* h2sb = (uint*)(ws + alloc((size_t)N * 8));   // bf16 h2*dis, 32B rows
    int* src = (int*)(ws + alloc(E));
    int* rowptr = (int*)(ws + alloc(N + 1));
    int* cnt = (int*)(ws + alloc(N));
    int* pos = (int*)(ws + alloc(N));
    int* bsum = (int*)(ws + alloc(1024));
    int* boff = (int*)(ws + alloc(1024));

    const int B = 256;

    // ---- CSR build + degrees ----
    k_zero_int<<<(N + B - 1) / B, B, 0, stream>>>(cnt, N);
    k_hist<<<(E + B - 1) / B, B, 0, stream>>>(col, cnt, E);
    k_blocksum<<<NB, 256, 0, stream>>>(cnt, bsum, N);
    k_scan_bsum<<<1, 512, 0, stream>>>(bsum, boff, NB, rowptr, N, E);
    k_scan_final<<<NB, 256, 0, stream>>>(cnt, boff, rowptr, pos, dis, N);
    k_fill<<<(E + B - 1) / B, B, 0, stream>>>(row, col, pos, src, E);

    // ---- layer 1 (aggregate bf16 xs, then transform) ----
    k_xs<<<(N * 8 + B - 1) / B, B, 0, stream>>>(x, dis, xsb, N * 8);
    k_l1<<<(N + 3) / 4, 256, 0, stream>>>(xsb, src, rowptr, dis, W1, b1, hb, N);

    // ---- layer 2 transform (pre-scaled bf16 messages) ----
    k_h2s<<<(N * 5 + B - 1) / B, B, 0, stream>>>(hb, W2, dis, h2sb, N);

    // ---- layer 2 aggregate + log-softmax + mean ----
    k_zero_out<<<1, 64, 0, stream>>>(out);
    k_lsm2<<<NB, 256, 0, stream>>>(h2sb, src, rowptr, dis, b2, out, N, 1.0f / (float)N);
}